// Round 20
// baseline (134.165 us; speedup 1.0000x reference)
//
#include <hip/hip_runtime.h>
#include <math.h>

typedef __attribute__((ext_vector_type(2))) float f32x2;
typedef __attribute__((ext_vector_type(4))) float fx4;
typedef __attribute__((ext_vector_type(8))) short s16x8;

#define EC 64        // edge chunks
#define NRR 8        // node ranges
#define RRN 6250     // nodes per range

// ================= bf16 helpers =================

__device__ __forceinline__ unsigned pack_bf2(float lo, float hi){
  unsigned ul = __float_as_uint(lo); ul += 0x7fffu + ((ul>>16)&1u);
  unsigned uh = __float_as_uint(hi); uh += 0x7fffu + ((uh>>16)&1u);
  return (uh & 0xffff0000u) | (ul >> 16);
}

// ================= GEMM core, f32 input (split hi/lo) — layer 1 =================

__device__ __forceinline__ void gemm_core(uint4* Wl, const float* __restrict__ X,
    const float* __restrict__ b, unsigned short* __restrict__ Ybf, int nrows, int brow, int t)
{
  int wv = t >> 6, lane = t & 63;
  int r = lane & 15, kb = lane >> 4;
  int row = brow*64 + wv*16 + r;
  const float* xrow = &X[(size_t)min(row, nrows-1)*128];

  fx4 acc[8];
  #pragma unroll
  for(int c=0;c<8;c++) acc[c] = (fx4){0.f,0.f,0.f,0.f};

  #pragma unroll
  for(int kt=0;kt<4;kt++){
    int k0 = kt*32 + kb*8;
    float4 v0 = *(const float4*)&xrow[k0];
    float4 v1 = *(const float4*)&xrow[k0+4];
    float vs[8] = {v0.x,v0.y,v0.z,v0.w,v1.x,v1.y,v1.z,v1.w};
    s16x8 ahi, alo;
    #pragma unroll
    for(int j=0;j<8;j++){
      unsigned u = __float_as_uint(vs[j]);
      unsigned uh = u + 0x7fffu + ((u>>16)&1u);
      unsigned short h = (unsigned short)(uh >> 16);
      float hf = __uint_as_float(((unsigned)h)<<16);
      float lo = vs[j] - hf;
      unsigned ul = __float_as_uint(lo);
      ul += 0x7fffu + ((ul>>16)&1u);
      ahi[j] = (short)h;
      alo[j] = (short)(ul>>16);
    }
    int chunk = kt*4 + kb;
    #pragma unroll
    for(int c=0;c<8;c++){
      uint4 wb = Wl[((c*16 + r)<<4) | (chunk ^ r)];
      s16x8 bb = *(s16x8*)&wb;
      acc[c] = __builtin_amdgcn_mfma_f32_16x16x32_bf16(ahi, bb, acc[c], 0,0,0);
      acc[c] = __builtin_amdgcn_mfma_f32_16x16x32_bf16(alo, bb, acc[c], 0,0,0);
    }
  }

  __syncthreads();
  unsigned short* lds = (unsigned short*)Wl;
  unsigned short* my = lds + wv*2048;
  int colb = lane & 15;
  int rq0 = (lane>>4)*4;
  #pragma unroll
  for(int c=0;c<8;c++){
    int col = c*16 + colb;
    float bias = b[col];
    #pragma unroll
    for(int q=0;q<4;q++){
      unsigned u = __float_as_uint(acc[c][q] + bias);
      u += 0x7fffu + ((u>>16)&1u);
      my[(rq0+q)*128 + col] = (unsigned short)(u>>16);
    }
  }
  const uint4* my4 = (const uint4*)my;
  uint4* Y4 = (uint4*)Ybf;
  #pragma unroll
  for(int rr=0;rr<4;rr++){
    int idx = lane + 64*rr;
    int lrow = idx >> 4, lcol = idx & 15;
    int grow = brow*64 + wv*16 + lrow;
    if(grow < nrows)
      Y4[(size_t)grow*16 + lcol] = my4[idx];
  }
}

// ================= hist: fire-and-forget LDS histogram =================

__global__ __launch_bounds__(256) void hist_k(
    const int* __restrict__ dst, int E, int CH,
    unsigned short* __restrict__ cnt16, int N)
{
  __shared__ int smem[RRN];
  int b = blockIdx.x;
  int t = threadIdx.x;
  int r = b >> 6, c = b & (EC-1);
  int r0 = r*RRN, rend = min(r0+RRN, N);
  int rn = rend - r0;
  if(rn <= 0) return;
  for(int d=t; d<rn; d+=256) smem[d] = 0;
  __syncthreads();
  int e0 = c*CH, e1 = min(e0+CH, E);
  for(int e = e0+t; e < e1; e += 256){
    int d = dst[e];
    if(d >= r0 && d < rend) atomicAdd(&smem[d-r0], 1);
  }
  __syncthreads();
  unsigned short* outp = cnt16 + (size_t)c*N;
  for(int d=t; d<rn; d+=256) outp[r0+d] = (unsigned short)smem[d];
}

// ================= scan1 =================

__global__ __launch_bounds__(1024) void scan1_k(const unsigned short* __restrict__ cnt16,
    unsigned short* __restrict__ offs16, int* __restrict__ total,
    int* __restrict__ bsum, int n){
  __shared__ int ws[16];
  int i = blockIdx.x*1024 + threadIdx.x;
  int v = 0;
  if(i < n){
    int s = 0;
    #pragma unroll
    for(int c=0;c<EC;c++){
      int tc = cnt16[(size_t)c*n + i];
      offs16[(size_t)c*n + i] = (unsigned short)s;
      s += tc;
    }
    total[i] = s;
    v = s;
  }
  #pragma unroll
  for(int m=1;m<64;m<<=1) v += __shfl_xor(v, m);
  if((threadIdx.x & 63) == 0) ws[threadIdx.x >> 6] = v;
  __syncthreads();
  if(threadIdx.x == 0){
    int s = 0;
    #pragma unroll
    for(int w=0; w<16; w++) s += ws[w];
    bsum[blockIdx.x] = s;
  }
}

// ================= scan3 (merged scan2) =================

__global__ __launch_bounds__(1024) void scan3_k(const int* __restrict__ total,
    const int* __restrict__ bsum, int nb, int* __restrict__ row_ptr, int n){
  __shared__ int sm[1024];
  __shared__ int base_s;
  int t = threadIdx.x;
  if(t < 64){
    int bv = (t < nb && t < (int)blockIdx.x) ? bsum[t] : 0;
    #pragma unroll
    for(int m=1;m<64;m<<=1) bv += __shfl_xor(bv, m);
    if(t == 0) base_s = bv;
  }
  int i = blockIdx.x*1024 + t;
  int v = (i<n)? total[i] : 0;
  sm[t] = v;
  __syncthreads();
  for(int off=1; off<1024; off<<=1){
    int tv = (t>=off)? sm[t-off] : 0;
    __syncthreads();
    sm[t] += tv;
    __syncthreads();
  }
  if(i<n){
    row_ptr[i] = sm[t] - v + base_s;
    if(i == n-1) row_ptr[n] = sm[t] + base_s;
  }
}

// ================= fillgemm: fillC (8-deep batched) || gemm1 || W2 conv || fold =================

__global__ __launch_bounds__(256) void fillgemm_k(
    const float* __restrict__ X, const float* __restrict__ W1, const float* __restrict__ b1,
    unsigned short* __restrict__ XWbf, int nrows, int nGB,
    const int* __restrict__ src, const int* __restrict__ dst,
    const unsigned short* __restrict__ offs16, const int* __restrict__ row_ptr,
    int* __restrict__ csr_src, int E, int CH, int N,
    const float* __restrict__ W2, unsigned short* __restrict__ W2bf,
    const float* __restrict__ Wp1, const float* __restrict__ bp1,
    const float* __restrict__ Wp2, const float* __restrict__ bp2,
    float* __restrict__ wfold)
{
  __shared__ int smem[8192];   // 32KB union: gemm Wl / fill cursors (25KB)
  int b = blockIdx.x;
  int t = threadIdx.x;

  if(b < nGB){
    uint4* Wl = (uint4*)smem;
    #pragma unroll
    for(int i=0;i<8;i++){
      int idx = t + i*256;
      int row = idx >> 4, ch = idx & 15;
      const float* wsrc = &W1[(size_t)row*128 + ch*8];
      float4 va = *(const float4*)&wsrc[0];
      float4 vb = *(const float4*)&wsrc[4];
      uint4 o;
      o.x = pack_bf2(va.x, va.y); o.y = pack_bf2(va.z, va.w);
      o.z = pack_bf2(vb.x, vb.y); o.w = pack_bf2(vb.z, vb.w);
      Wl[(row<<4) | (ch ^ (row & 15))] = o;
    }
    __syncthreads();
    gemm_core(Wl, X, b1, XWbf, nrows, b, t);
    return;
  }
  int fb = b - nGB;
  if(fb < NRR*EC){
    int* cursor = smem;
    int r = fb >> 6, c = fb & (EC-1);
    int r0 = r*RRN, rend = min(r0+RRN, N);
    int rn = rend - r0;
    if(rn <= 0) return;
    for(int d=t; d<rn; d+=256)
      cursor[d] = row_ptr[r0+d] + (int)offs16[(size_t)c*N + r0 + d];
    __syncthreads();
    int e0 = c*CH, e1 = min(e0+CH, E);
    for(int base = e0 + t; base < e1; base += 2048){
      int dd[8], ss[8];
      #pragma unroll
      for(int q=0;q<8;q++){
        int e = base + q*256;
        dd[q] = (e < e1) ? dst[e] : -1;
      }
      #pragma unroll
      for(int q=0;q<8;q++){
        int e = base + q*256;
        ss[q] = (e < e1) ? src[e] : 0;
      }
      #pragma unroll
      for(int q=0;q<8;q++){
        if(dd[q] >= r0 && dd[q] < rend){
          int p = atomicAdd(&cursor[dd[q]-r0], 1);
          csr_src[p] = ss[q];
        }
      }
    }
    return;
  }
  int tb = fb - NRR*EC;
  if(tb == 0){
    const float4* Ws = (const float4*)W2;
    uint2* Wd = (uint2*)W2bf;
    #pragma unroll
    for(int i=0;i<16;i++){
      int idx = t + i*256;
      float4 v = Ws[idx];
      uint2 o; o.x = pack_bf2(v.x, v.y); o.y = pack_bf2(v.z, v.w);
      Wd[idx] = o;
    }
    return;
  }
  int k = t;
  if(k < 128){
    float s = 0.f;
    for(int j=0;j<64;j++) s += Wp2[j]*Wp1[(size_t)j*128 + k];
    wfold[k] = s;
  } else if(k == 128){
    float s = bp2[0];
    for(int j=0;j<64;j++) s += Wp2[j]*bp1[j];
    wfold[128] = s;
  }
}

// ================= layer-2 GEMM: bf16 input, single MFMA =================

__global__ __launch_bounds__(256) void gemm_bf2_k(
    const unsigned short* __restrict__ Xbf, const unsigned short* __restrict__ Wbf,
    const float* __restrict__ b, unsigned short* __restrict__ Ybf, int nrows)
{
  __shared__ uint4 Wl[128*16];
  int t = threadIdx.x;
  {
    const uint4* Ws = (const uint4*)Wbf;
    #pragma unroll
    for(int i=0;i<8;i++){
      int idx = t + i*256;
      int row = idx >> 4, ch = idx & 15;
      Wl[(row<<4) | (ch ^ (row & 15))] = Ws[idx];
    }
  }
  __syncthreads();

  int wv = t >> 6, lane = t & 63;
  int r = lane & 15, kb = lane >> 4;
  int row = blockIdx.x*64 + wv*16 + r;
  const uint4* xrow = (const uint4*)&Xbf[(size_t)min(row, nrows-1)*128];

  fx4 acc[8];
  #pragma unroll
  for(int c=0;c<8;c++) acc[c] = (fx4){0.f,0.f,0.f,0.f};

  #pragma unroll
  for(int kt=0;kt<4;kt++){
    uint4 av = xrow[kt*4 + kb];
    s16x8 aa = *(s16x8*)&av;
    int chunk = kt*4 + kb;
    #pragma unroll
    for(int c=0;c<8;c++){
      uint4 wb = Wl[((c*16 + r)<<4) | (chunk ^ r)];
      s16x8 bb = *(s16x8*)&wb;
      acc[c] = __builtin_amdgcn_mfma_f32_16x16x32_bf16(aa, bb, acc[c], 0,0,0);
    }
  }

  __syncthreads();
  unsigned short* lds = (unsigned short*)Wl;
  unsigned short* my = lds + wv*2048;
  int colb = lane & 15;
  int rq0 = (lane>>4)*4;
  #pragma unroll
  for(int c=0;c<8;c++){
    int col = c*16 + colb;
    float bias = b[col];
    #pragma unroll
    for(int q=0;q<4;q++){
      unsigned u = __float_as_uint(acc[c][q] + bias);
      u += 0x7fffu + ((u>>16)&1u);
      my[(rq0+q)*128 + col] = (unsigned short)(u>>16);
    }
  }
  const uint4* my4 = (const uint4*)my;
  uint4* Y4 = (uint4*)Ybf;
  #pragma unroll
  for(int rr=0;rr<4;rr++){
    int idx = lane + 64*rr;
    int lrow = idx >> 4, lcol = idx & 15;
    int grow = blockIdx.x*64 + wv*16 + lrow;
    if(grow < nrows)
      Y4[(size_t)grow*16 + lcol] = my4[idx];
  }
}

// ================= GATv2 edge phase v7 =================

#define BFLO(u) __uint_as_float((u)<<16)
#define BFHI(u) __uint_as_float((u)&0xffff0000u)
#define DPP_ADD(v, ctrl) { int _t = __builtin_amdgcn_update_dpp(0, __float_as_int(v), ctrl, 0xF, 0xF, true); (v) += __int_as_float(_t); }
#define EXP2RAW(x) __builtin_amdgcn_exp2f(x)

#define GAT_BODY(U, EXPR_EX) { \
  f32x2 x0 = {BFLO(U.x), BFHI(U.x)}; \
  f32x2 x1 = {BFLO(U.y), BFHI(U.y)}; \
  f32x2 x2 = {BFLO(U.z), BFHI(U.z)}; \
  f32x2 x3 = {BFLO(U.w), BFHI(U.w)}; \
  f32x2 v0 = xd[0]+x0, v1 = xd[1]+x1, v2 = xd[2]+x2, v3 = xd[3]+x3; \
  f32x2 l0 = __builtin_elementwise_max(v0, v0*0.2f); \
  f32x2 l1 = __builtin_elementwise_max(v1, v1*0.2f); \
  f32x2 l2 = __builtin_elementwise_max(v2, v2*0.2f); \
  f32x2 l3 = __builtin_elementwise_max(v3, v3*0.2f); \
  f32x2 p2 = l0*a[0]; p2 += l1*a[1]; p2 += l2*a[2]; p2 += l3*a[3]; \
  float p = p2.x + p2.y; \
  DPP_ADD(p, 0xB1); \
  DPP_ADD(p, 0x4E); \
  DPP_ADD(p, 0x141); \
  float ex = (EXPR_EX); \
  s += ex; \
  f32x2 e2 = {ex, ex}; \
  acc[0] += e2*x0; acc[1] += e2*x1; acc[2] += e2*x2; acc[3] += e2*x3; }

template<int FUSE>
__global__ __launch_bounds__(256) void gat_v7_k(
    const unsigned short* __restrict__ XWbf,
    const float* __restrict__ att,
    const int* __restrict__ row_ptr, const int* __restrict__ csr_src,
    float* __restrict__ outf, unsigned short* __restrict__ outbf,
    const float* __restrict__ wfold, int n)
{
  int wid = threadIdx.x >> 6, lane = threadIdx.x & 63;
  int node = blockIdx.x*4 + wid;
  if(node >= n) return;
  int g = lane >> 4;
  int cg = lane & 15;
  int c8 = cg * 8;

  const float L2E = 1.44269504088896f;
  float4 A0 = *(const float4*)&att[c8];
  float4 A1 = *(const float4*)&att[c8+4];
  f32x2 a[4] = { {A0.x*L2E,A0.y*L2E}, {A0.z*L2E,A0.w*L2E},
                 {A1.x*L2E,A1.y*L2E}, {A1.z*L2E,A1.w*L2E} };

  const uint4* XW4 = (const uint4*)XWbf;
  uint4 du = XW4[(size_t)node*16 + cg];
  f32x2 xd[4] = { {BFLO(du.x),BFHI(du.x)}, {BFLO(du.y),BFHI(du.y)},
                  {BFLO(du.z),BFHI(du.z)}, {BFLO(du.w),BFHI(du.w)} };

  int beg = row_ptr[node], end = row_ptr[node+1];
  float s = 0.f;
  f32x2 acc[4] = {{0.f,0.f},{0.f,0.f},{0.f,0.f},{0.f,0.f}};

  if(end > beg){
    int i = beg;
    int sn0 = csr_src[min(beg + g, end-1)];
    uint4 u = XW4[(size_t)sn0*16 + cg];
    int sn1 = (beg+4 < end) ? csr_src[min(beg+4 + g, end-1)] : sn0;

    for(; i + 4 <= end; i += 4){
      uint4 un = XW4[(size_t)sn1*16 + cg];
      int sn2 = (i+8 < end) ? csr_src[min(i+8 + g, end-1)] : sn1;
      GAT_BODY(u, EXP2RAW(p));
      u = un; sn1 = sn2;
    }
    if(i < end){
      bool ok = (i + g) < end;
      GAT_BODY(u, ok ? EXP2RAW(p) : 0.f);
    }
  }

  s += __shfl_xor(s,16);  s += __shfl_xor(s,32);
  #pragma unroll
  for(int j=0;j<4;j++){
    acc[j].x += __shfl_xor(acc[j].x,16); acc[j].x += __shfl_xor(acc[j].x,32);
    acc[j].y += __shfl_xor(acc[j].y,16); acc[j].y += __shfl_xor(acc[j].y,32);
  }

  float inv = (s > 0.f) ? 1.f/s : 0.f;
  f32x2 o[4];
  #pragma unroll
  for(int j=0;j<4;j++){
    o[j].x = fmaxf(acc[j].x*inv, 0.f);
    o[j].y = fmaxf(acc[j].y*inv, 0.f);
  }

  if(FUSE == 0){
    if(lane < 16){
      uint4 o4;
      o4.x = pack_bf2(o[0].x, o[0].y);
      o4.y = pack_bf2(o[1].x, o[1].y);
      o4.z = pack_bf2(o[2].x, o[2].y);
      o4.w = pack_bf2(o[3].x, o[3].y);
      *(uint4*)&outbf[(size_t)node*128 + c8] = o4;
    }
  } else {
    float4 wf0 = *(const float4*)&wfold[c8];
    float4 wf1 = *(const float4*)&wfold[c8+4];
    float tt = o[0].x*wf0.x + o[0].y*wf0.y + o[1].x*wf0.z + o[1].y*wf0.w
             + o[2].x*wf1.x + o[2].y*wf1.y + o[3].x*wf1.z + o[3].y*wf1.w;
    DPP_ADD(tt, 0xB1);
    DPP_ADD(tt, 0x4E);
    DPP_ADD(tt, 0x141);
    DPP_ADD(tt, 0x140);
    if(lane == 0)
      outf[node] = 1.f/(1.f + __expf(-(tt + wfold[128])));
  }
}

// ================= launcher =================

static inline size_t alignup(size_t v){ return (v + 255) & ~(size_t)255; }

extern "C" void kernel_launch(void* const* d_in, const int* in_sizes, int n_in,
                              void* d_out, int out_size, void* d_ws, size_t ws_size,
                              hipStream_t stream) {
  const float* x    = (const float*)d_in[0];
  const int*   ei   = (const int*)  d_in[1];
  const float* W1   = (const float*)d_in[2];
  const float* b1   = (const float*)d_in[3];
  const float* att1 = (const float*)d_in[4];
  const float* W2   = (const float*)d_in[5];
  const float* b2   = (const float*)d_in[6];
  const float* att2 = (const float*)d_in[7];
  const float* Wp1  = (const float*)d_in[8];
  const float* bp1  = (const float*)d_in[9];
  const float* Wp2  = (const float*)d_in[10];
  const float* bp2  = (const float*)d_in[11];
  float* out = (float*)d_out;

  int N = in_sizes[0] / 128;
  int E = in_sizes[1] / 2;
  int CH = (E + EC - 1) / EC;

  char* ws = (char*)d_ws;
  size_t off = 0;
  unsigned short* Gbf  = (unsigned short*)(ws + off); off = alignup(off + (size_t)N*128*sizeof(unsigned short));
  unsigned short* XWbf = (unsigned short*)(ws + off); off = alignup(off + (size_t)N*128*sizeof(unsigned short));
  int* csr_src  = (int*)(ws + off); off = alignup(off + (size_t)E*sizeof(int));
  unsigned short* cnt16  = (unsigned short*)(ws + off); off = alignup(off + (size_t)EC*N*sizeof(unsigned short));
  unsigned short* offs16 = (unsigned short*)(ws + off); off = alignup(off + (size_t)EC*N*sizeof(unsigned short));
  int* row_ptr  = (int*)(ws + off); off = alignup(off + (size_t)(N+1)*sizeof(int));
  int* total    = (int*)(ws + off); off = alignup(off + (size_t)N*sizeof(int));
  int* bsum     = (int*)(ws + off); off = alignup(off + 1024*sizeof(int));
  unsigned short* W2bf = (unsigned short*)(ws + off); off = alignup(off + 128*128*sizeof(unsigned short));
  float* wfold  = (float*)(ws + off); off = alignup(off + 129*sizeof(float));

  const int* esrc = ei;
  const int* edst = ei + E;

  int nGB = (N + 63) / 64;
  int nb = (N + 1023) / 1024;

  // CSR phase A: histogram only (fast, alone)
  hist_k<<<NRR*EC, 256, 0, stream>>>(edst, E, CH, cnt16, N);
  scan1_k<<<nb, 1024, 0, stream>>>(cnt16, offs16, total, bsum, N);
  scan3_k<<<nb, 1024, 0, stream>>>(total, bsum, nb, row_ptr, N);
  // fillC (8-deep) || gemm1 || W2 convert || fold — independent work co-scheduled
  fillgemm_k<<<nGB + NRR*EC + 2, 256, 0, stream>>>(
      x, W1, b1, XWbf, N, nGB,
      esrc, edst, offs16, row_ptr, csr_src, E, CH, N,
      W2, W2bf, Wp1, bp1, Wp2, bp2, wfold);

  // layer 1 edge phase -> bf16 h
  gat_v7_k<0><<<(N+3)/4, 256, 0, stream>>>(XWbf, att1, row_ptr, csr_src, nullptr, Gbf, nullptr, N);
  // layer 2 gemm: bf16 in, bf16 out
  gemm_bf2_k<<<nGB, 256, 0, stream>>>(Gbf, W2bf, b2, XWbf, N);
  // layer 2 edge phase + folded MLP + sigmoid
  gat_v7_k<1><<<(N+3)/4, 256, 0, stream>>>(XWbf, att2, row_ptr, csr_src, out, nullptr, wfold, N);
}

// Round 21
// 131.863 us; speedup vs baseline: 1.0175x; 1.0175x over previous
//
#include <hip/hip_runtime.h>
#include <math.h>

typedef __attribute__((ext_vector_type(2))) float f32x2;
typedef __attribute__((ext_vector_type(4))) float fx4;
typedef __attribute__((ext_vector_type(8))) short s16x8;

#define EC 64        // edge chunks
#define NRR 8        // node ranges
#define RRN 6250     // nodes per range

// ================= bf16 helpers =================

__device__ __forceinline__ unsigned pack_bf2(float lo, float hi){
  unsigned ul = __float_as_uint(lo); ul += 0x7fffu + ((ul>>16)&1u);
  unsigned uh = __float_as_uint(hi); uh += 0x7fffu + ((uh>>16)&1u);
  return (uh & 0xffff0000u) | (ul >> 16);
}

// ================= GEMM core, f32 input (split hi/lo) — layer 1 =================

__device__ __forceinline__ void gemm_core(uint4* Wl, const float* __restrict__ X,
    const float* __restrict__ b, unsigned short* __restrict__ Ybf, int nrows, int brow, int t)
{
  int wv = t >> 6, lane = t & 63;
  int r = lane & 15, kb = lane >> 4;
  int row = brow*64 + wv*16 + r;
  const float* xrow = &X[(size_t)min(row, nrows-1)*128];

  fx4 acc[8];
  #pragma unroll
  for(int c=0;c<8;c++) acc[c] = (fx4){0.f,0.f,0.f,0.f};

  #pragma unroll
  for(int kt=0;kt<4;kt++){
    int k0 = kt*32 + kb*8;
    float4 v0 = *(const float4*)&xrow[k0];
    float4 v1 = *(const float4*)&xrow[k0+4];
    float vs[8] = {v0.x,v0.y,v0.z,v0.w,v1.x,v1.y,v1.z,v1.w};
    s16x8 ahi, alo;
    #pragma unroll
    for(int j=0;j<8;j++){
      unsigned u = __float_as_uint(vs[j]);
      unsigned uh = u + 0x7fffu + ((u>>16)&1u);
      unsigned short h = (unsigned short)(uh >> 16);
      float hf = __uint_as_float(((unsigned)h)<<16);
      float lo = vs[j] - hf;
      unsigned ul = __float_as_uint(lo);
      ul += 0x7fffu + ((ul>>16)&1u);
      ahi[j] = (short)h;
      alo[j] = (short)(ul>>16);
    }
    int chunk = kt*4 + kb;
    #pragma unroll
    for(int c=0;c<8;c++){
      uint4 wb = Wl[((c*16 + r)<<4) | (chunk ^ r)];
      s16x8 bb = *(s16x8*)&wb;
      acc[c] = __builtin_amdgcn_mfma_f32_16x16x32_bf16(ahi, bb, acc[c], 0,0,0);
      acc[c] = __builtin_amdgcn_mfma_f32_16x16x32_bf16(alo, bb, acc[c], 0,0,0);
    }
  }

  __syncthreads();
  unsigned short* lds = (unsigned short*)Wl;
  unsigned short* my = lds + wv*2048;
  int colb = lane & 15;
  int rq0 = (lane>>4)*4;
  #pragma unroll
  for(int c=0;c<8;c++){
    int col = c*16 + colb;
    float bias = b[col];
    #pragma unroll
    for(int q=0;q<4;q++){
      unsigned u = __float_as_uint(acc[c][q] + bias);
      u += 0x7fffu + ((u>>16)&1u);
      my[(rq0+q)*128 + col] = (unsigned short)(u>>16);
    }
  }
  const uint4* my4 = (const uint4*)my;
  uint4* Y4 = (uint4*)Ybf;
  #pragma unroll
  for(int rr=0;rr<4;rr++){
    int idx = lane + 64*rr;
    int lrow = idx >> 4, lcol = idx & 15;
    int grow = brow*64 + wv*16 + lrow;
    if(grow < nrows)
      Y4[(size_t)grow*16 + lcol] = my4[idx];
  }
}

// ================= mega: gemm1 || fire-and-forget LDS histogram || W2 conv || fold =================

__global__ __launch_bounds__(256) void mega_k(
    const float* __restrict__ X, const float* __restrict__ W1, const float* __restrict__ b1,
    unsigned short* __restrict__ XWbf, int nrows, int nGB,
    const int* __restrict__ dst, int E, int CH,
    unsigned short* __restrict__ cnt16, int N,
    const float* __restrict__ W2, unsigned short* __restrict__ W2bf,
    const float* __restrict__ Wp1, const float* __restrict__ bp1,
    const float* __restrict__ Wp2, const float* __restrict__ bp2,
    float* __restrict__ wfold)
{
  __shared__ int smem[8192];
  int b = blockIdx.x;
  int t = threadIdx.x;

  if(b < nGB){
    uint4* Wl = (uint4*)smem;
    #pragma unroll
    for(int i=0;i<8;i++){
      int idx = t + i*256;
      int row = idx >> 4, ch = idx & 15;
      const float* wsrc = &W1[(size_t)row*128 + ch*8];
      float4 va = *(const float4*)&wsrc[0];
      float4 vb = *(const float4*)&wsrc[4];
      uint4 o;
      o.x = pack_bf2(va.x, va.y); o.y = pack_bf2(va.z, va.w);
      o.z = pack_bf2(vb.x, vb.y); o.w = pack_bf2(vb.z, vb.w);
      Wl[(row<<4) | (ch ^ (row & 15))] = o;
    }
    __syncthreads();
    gemm_core(Wl, X, b1, XWbf, nrows, b, t);
    return;
  }
  int hb = b - nGB;
  if(hb < NRR*EC){
    int r = hb >> 6, c = hb & (EC-1);
    int r0 = r*RRN, rend = min(r0+RRN, N);
    int rn = rend - r0;
    if(rn <= 0) return;
    for(int d=t; d<rn; d+=256) smem[d] = 0;
    __syncthreads();
    int e0 = c*CH, e1 = min(e0+CH, E);
    for(int e = e0+t; e < e1; e += 256){
      int d = dst[e];
      if(d >= r0 && d < rend) atomicAdd(&smem[d-r0], 1);
    }
    __syncthreads();
    unsigned short* outp = cnt16 + (size_t)c*N;
    for(int d=t; d<rn; d+=256) outp[r0+d] = (unsigned short)smem[d];
    return;
  }
  int tb = hb - NRR*EC;
  if(tb == 0){
    const float4* Ws = (const float4*)W2;
    uint2* Wd = (uint2*)W2bf;
    #pragma unroll
    for(int i=0;i<16;i++){
      int idx = t + i*256;
      float4 v = Ws[idx];
      uint2 o; o.x = pack_bf2(v.x, v.y); o.y = pack_bf2(v.z, v.w);
      Wd[idx] = o;
    }
    return;
  }
  int k = t;
  if(k < 128){
    float s = 0.f;
    for(int j=0;j<64;j++) s += Wp2[j]*Wp1[(size_t)j*128 + k];
    wfold[k] = s;
  } else if(k == 128){
    float s = bp2[0];
    for(int j=0;j<64;j++) s += Wp2[j]*bp1[j];
    wfold[128] = s;
  }
}

// ================= scan1 =================

__global__ __launch_bounds__(1024) void scan1_k(const unsigned short* __restrict__ cnt16,
    unsigned short* __restrict__ offs16, int* __restrict__ total,
    int* __restrict__ bsum, int n){
  __shared__ int ws[16];
  int i = blockIdx.x*1024 + threadIdx.x;
  int v = 0;
  if(i < n){
    int s = 0;
    #pragma unroll
    for(int c=0;c<EC;c++){
      int tc = cnt16[(size_t)c*n + i];
      offs16[(size_t)c*n + i] = (unsigned short)s;
      s += tc;
    }
    total[i] = s;
    v = s;
  }
  #pragma unroll
  for(int m=1;m<64;m<<=1) v += __shfl_xor(v, m);
  if((threadIdx.x & 63) == 0) ws[threadIdx.x >> 6] = v;
  __syncthreads();
  if(threadIdx.x == 0){
    int s = 0;
    #pragma unroll
    for(int w=0; w<16; w++) s += ws[w];
    bsum[blockIdx.x] = s;
  }
}

// ================= scan3 (merged scan2) =================

__global__ __launch_bounds__(1024) void scan3_k(const int* __restrict__ total,
    const int* __restrict__ bsum, int nb, int* __restrict__ row_ptr, int n){
  __shared__ int sm[1024];
  __shared__ int base_s;
  int t = threadIdx.x;
  if(t < 64){
    int bv = (t < nb && t < (int)blockIdx.x) ? bsum[t] : 0;
    #pragma unroll
    for(int m=1;m<64;m<<=1) bv += __shfl_xor(bv, m);
    if(t == 0) base_s = bv;
  }
  int i = blockIdx.x*1024 + t;
  int v = (i<n)? total[i] : 0;
  sm[t] = v;
  __syncthreads();
  for(int off=1; off<1024; off<<=1){
    int tv = (t>=off)? sm[t-off] : 0;
    __syncthreads();
    sm[t] += tv;
    __syncthreads();
  }
  if(i<n){
    row_ptr[i] = sm[t] - v + base_s;
    if(i == n-1) row_ptr[n] = sm[t] + base_s;
  }
}

// ================= fillC: LDS cursors, 8-deep batched loads =================

__global__ __launch_bounds__(256) void fillC_k(
    const int* __restrict__ src, const int* __restrict__ dst,
    const unsigned short* __restrict__ offs16, const int* __restrict__ row_ptr,
    int* __restrict__ csr_src, int E, int CH, int N)
{
  __shared__ int cursor[RRN];
  int b = blockIdx.x, t = threadIdx.x;
  int r = b >> 6, c = b & (EC-1);
  int r0 = r*RRN, rend = min(r0+RRN, N);
  int rn = rend - r0;
  if(rn <= 0) return;
  for(int d=t; d<rn; d+=256)
    cursor[d] = row_ptr[r0+d] + (int)offs16[(size_t)c*N + r0 + d];
  __syncthreads();
  int e0 = c*CH, e1 = min(e0+CH, E);
  for(int base = e0 + t; base < e1; base += 2048){
    int dd[8], ss[8];
    #pragma unroll
    for(int q=0;q<8;q++){
      int e = base + q*256;
      dd[q] = (e < e1) ? dst[e] : -1;
    }
    #pragma unroll
    for(int q=0;q<8;q++){
      int e = base + q*256;
      ss[q] = (e < e1) ? src[e] : 0;
    }
    #pragma unroll
    for(int q=0;q<8;q++){
      if(dd[q] >= r0 && dd[q] < rend){
        int p = atomicAdd(&cursor[dd[q]-r0], 1);
        csr_src[p] = ss[q];
      }
    }
  }
}

// ================= layer-2 GEMM: bf16 input, single MFMA =================

__global__ __launch_bounds__(256) void gemm_bf2_k(
    const unsigned short* __restrict__ Xbf, const unsigned short* __restrict__ Wbf,
    const float* __restrict__ b, unsigned short* __restrict__ Ybf, int nrows)
{
  __shared__ uint4 Wl[128*16];
  int t = threadIdx.x;
  {
    const uint4* Ws = (const uint4*)Wbf;
    #pragma unroll
    for(int i=0;i<8;i++){
      int idx = t + i*256;
      int row = idx >> 4, ch = idx & 15;
      Wl[(row<<4) | (ch ^ (row & 15))] = Ws[idx];
    }
  }
  __syncthreads();

  int wv = t >> 6, lane = t & 63;
  int r = lane & 15, kb = lane >> 4;
  int row = blockIdx.x*64 + wv*16 + r;
  const uint4* xrow = (const uint4*)&Xbf[(size_t)min(row, nrows-1)*128];

  fx4 acc[8];
  #pragma unroll
  for(int c=0;c<8;c++) acc[c] = (fx4){0.f,0.f,0.f,0.f};

  #pragma unroll
  for(int kt=0;kt<4;kt++){
    uint4 av = xrow[kt*4 + kb];
    s16x8 aa = *(s16x8*)&av;
    int chunk = kt*4 + kb;
    #pragma unroll
    for(int c=0;c<8;c++){
      uint4 wb = Wl[((c*16 + r)<<4) | (chunk ^ r)];
      s16x8 bb = *(s16x8*)&wb;
      acc[c] = __builtin_amdgcn_mfma_f32_16x16x32_bf16(aa, bb, acc[c], 0,0,0);
    }
  }

  __syncthreads();
  unsigned short* lds = (unsigned short*)Wl;
  unsigned short* my = lds + wv*2048;
  int colb = lane & 15;
  int rq0 = (lane>>4)*4;
  #pragma unroll
  for(int c=0;c<8;c++){
    int col = c*16 + colb;
    float bias = b[col];
    #pragma unroll
    for(int q=0;q<4;q++){
      unsigned u = __float_as_uint(acc[c][q] + bias);
      u += 0x7fffu + ((u>>16)&1u);
      my[(rq0+q)*128 + col] = (unsigned short)(u>>16);
    }
  }
  const uint4* my4 = (const uint4*)my;
  uint4* Y4 = (uint4*)Ybf;
  #pragma unroll
  for(int rr=0;rr<4;rr++){
    int idx = lane + 64*rr;
    int lrow = idx >> 4, lcol = idx & 15;
    int grow = blockIdx.x*64 + wv*16 + lrow;
    if(grow < nrows)
      Y4[(size_t)grow*16 + lcol] = my4[idx];
  }
}

// ================= GATv2 edge phase v7 =================

#define BFLO(u) __uint_as_float((u)<<16)
#define BFHI(u) __uint_as_float((u)&0xffff0000u)
#define DPP_ADD(v, ctrl) { int _t = __builtin_amdgcn_update_dpp(0, __float_as_int(v), ctrl, 0xF, 0xF, true); (v) += __int_as_float(_t); }
#define EXP2RAW(x) __builtin_amdgcn_exp2f(x)

#define GAT_BODY(U, EXPR_EX) { \
  f32x2 x0 = {BFLO(U.x), BFHI(U.x)}; \
  f32x2 x1 = {BFLO(U.y), BFHI(U.y)}; \
  f32x2 x2 = {BFLO(U.z), BFHI(U.z)}; \
  f32x2 x3 = {BFLO(U.w), BFHI(U.w)}; \
  f32x2 v0 = xd[0]+x0, v1 = xd[1]+x1, v2 = xd[2]+x2, v3 = xd[3]+x3; \
  f32x2 l0 = __builtin_elementwise_max(v0, v0*0.2f); \
  f32x2 l1 = __builtin_elementwise_max(v1, v1*0.2f); \
  f32x2 l2 = __builtin_elementwise_max(v2, v2*0.2f); \
  f32x2 l3 = __builtin_elementwise_max(v3, v3*0.2f); \
  f32x2 p2 = l0*a[0]; p2 += l1*a[1]; p2 += l2*a[2]; p2 += l3*a[3]; \
  float p = p2.x + p2.y; \
  DPP_ADD(p, 0xB1); \
  DPP_ADD(p, 0x4E); \
  DPP_ADD(p, 0x141); \
  float ex = (EXPR_EX); \
  s += ex; \
  f32x2 e2 = {ex, ex}; \
  acc[0] += e2*x0; acc[1] += e2*x1; acc[2] += e2*x2; acc[3] += e2*x3; }

template<int FUSE>
__global__ __launch_bounds__(256) void gat_v7_k(
    const unsigned short* __restrict__ XWbf,
    const float* __restrict__ att,
    const int* __restrict__ row_ptr, const int* __restrict__ csr_src,
    float* __restrict__ outf, unsigned short* __restrict__ outbf,
    const float* __restrict__ wfold, int n)
{
  int wid = threadIdx.x >> 6, lane = threadIdx.x & 63;
  int node = blockIdx.x*4 + wid;
  if(node >= n) return;
  int g = lane >> 4;
  int cg = lane & 15;
  int c8 = cg * 8;

  const float L2E = 1.44269504088896f;
  float4 A0 = *(const float4*)&att[c8];
  float4 A1 = *(const float4*)&att[c8+4];
  f32x2 a[4] = { {A0.x*L2E,A0.y*L2E}, {A0.z*L2E,A0.w*L2E},
                 {A1.x*L2E,A1.y*L2E}, {A1.z*L2E,A1.w*L2E} };

  const uint4* XW4 = (const uint4*)XWbf;
  uint4 du = XW4[(size_t)node*16 + cg];
  f32x2 xd[4] = { {BFLO(du.x),BFHI(du.x)}, {BFLO(du.y),BFHI(du.y)},
                  {BFLO(du.z),BFHI(du.z)}, {BFLO(du.w),BFHI(du.w)} };

  int beg = row_ptr[node], end = row_ptr[node+1];
  float s = 0.f;
  f32x2 acc[4] = {{0.f,0.f},{0.f,0.f},{0.f,0.f},{0.f,0.f}};

  if(end > beg){
    int i = beg;
    int sn0 = csr_src[min(beg + g, end-1)];
    uint4 u = XW4[(size_t)sn0*16 + cg];
    int sn1 = (beg+4 < end) ? csr_src[min(beg+4 + g, end-1)] : sn0;

    for(; i + 4 <= end; i += 4){
      uint4 un = XW4[(size_t)sn1*16 + cg];
      int sn2 = (i+8 < end) ? csr_src[min(i+8 + g, end-1)] : sn1;
      GAT_BODY(u, EXP2RAW(p));
      u = un; sn1 = sn2;
    }
    if(i < end){
      bool ok = (i + g) < end;
      GAT_BODY(u, ok ? EXP2RAW(p) : 0.f);
    }
  }

  s += __shfl_xor(s,16);  s += __shfl_xor(s,32);
  #pragma unroll
  for(int j=0;j<4;j++){
    acc[j].x += __shfl_xor(acc[j].x,16); acc[j].x += __shfl_xor(acc[j].x,32);
    acc[j].y += __shfl_xor(acc[j].y,16); acc[j].y += __shfl_xor(acc[j].y,32);
  }

  float inv = (s > 0.f) ? 1.f/s : 0.f;
  f32x2 o[4];
  #pragma unroll
  for(int j=0;j<4;j++){
    o[j].x = fmaxf(acc[j].x*inv, 0.f);
    o[j].y = fmaxf(acc[j].y*inv, 0.f);
  }

  if(FUSE == 0){
    if(lane < 16){
      uint4 o4;
      o4.x = pack_bf2(o[0].x, o[0].y);
      o4.y = pack_bf2(o[1].x, o[1].y);
      o4.z = pack_bf2(o[2].x, o[2].y);
      o4.w = pack_bf2(o[3].x, o[3].y);
      *(uint4*)&outbf[(size_t)node*128 + c8] = o4;
    }
  } else {
    float4 wf0 = *(const float4*)&wfold[c8];
    float4 wf1 = *(const float4*)&wfold[c8+4];
    float tt = o[0].x*wf0.x + o[0].y*wf0.y + o[1].x*wf0.z + o[1].y*wf0.w
             + o[2].x*wf1.x + o[2].y*wf1.y + o[3].x*wf1.z + o[3].y*wf1.w;
    DPP_ADD(tt, 0xB1);
    DPP_ADD(tt, 0x4E);
    DPP_ADD(tt, 0x141);
    DPP_ADD(tt, 0x140);
    if(lane == 0)
      outf[node] = 1.f/(1.f + __expf(-(tt + wfold[128])));
  }
}

// ================= launcher =================

static inline size_t alignup(size_t v){ return (v + 255) & ~(size_t)255; }

extern "C" void kernel_launch(void* const* d_in, const int* in_sizes, int n_in,
                              void* d_out, int out_size, void* d_ws, size_t ws_size,
                              hipStream_t stream) {
  const float* x    = (const float*)d_in[0];
  const int*   ei   = (const int*)  d_in[1];
  const float* W1   = (const float*)d_in[2];
  const float* b1   = (const float*)d_in[3];
  const float* att1 = (const float*)d_in[4];
  const float* W2   = (const float*)d_in[5];
  const float* b2   = (const float*)d_in[6];
  const float* att2 = (const float*)d_in[7];
  const float* Wp1  = (const float*)d_in[8];
  const float* bp1  = (const float*)d_in[9];
  const float* Wp2  = (const float*)d_in[10];
  const float* bp2  = (const float*)d_in[11];
  float* out = (float*)d_out;

  int N = in_sizes[0] / 128;
  int E = in_sizes[1] / 2;
  int CH = (E + EC - 1) / EC;

  char* ws = (char*)d_ws;
  size_t off = 0;
  unsigned short* Gbf  = (unsigned short*)(ws + off); off = alignup(off + (size_t)N*128*sizeof(unsigned short));
  unsigned short* XWbf = (unsigned short*)(ws + off); off = alignup(off + (size_t)N*128*sizeof(unsigned short));
  int* csr_src  = (int*)(ws + off); off = alignup(off + (size_t)E*sizeof(int));
  unsigned short* cnt16  = (unsigned short*)(ws + off); off = alignup(off + (size_t)EC*N*sizeof(unsigned short));
  unsigned short* offs16 = (unsigned short*)(ws + off); off = alignup(off + (size_t)EC*N*sizeof(unsigned short));
  int* row_ptr  = (int*)(ws + off); off = alignup(off + (size_t)(N+1)*sizeof(int));
  int* total    = (int*)(ws + off); off = alignup(off + (size_t)N*sizeof(int));
  int* bsum     = (int*)(ws + off); off = alignup(off + 1024*sizeof(int));
  unsigned short* W2bf = (unsigned short*)(ws + off); off = alignup(off + 128*128*sizeof(unsigned short));
  float* wfold  = (float*)(ws + off); off = alignup(off + 129*sizeof(float));

  const int* esrc = ei;
  const int* edst = ei + E;

  int nGB = (N + 63) / 64;
  int nb = (N + 1023) / 1024;

  // gemm1 || CSR histogram (fire-and-forget) || W2 convert || fold
  mega_k<<<nGB + NRR*EC + 2, 256, 0, stream>>>(
      x, W1, b1, XWbf, N, nGB,
      edst, E, CH, cnt16, N,
      W2, W2bf, Wp1, bp1, Wp2, bp2, wfold);

  scan1_k<<<nb, 1024, 0, stream>>>(cnt16, offs16, total, bsum, N);
  scan3_k<<<nb, 1024, 0, stream>>>(total, bsum, nb, row_ptr, N);
  fillC_k<<<NRR*EC, 256, 0, stream>>>(esrc, edst, offs16, row_ptr, csr_src, E, CH, N);

  // layer 1 edge phase -> bf16 h
  gat_v7_k<0><<<(N+3)/4, 256, 0, stream>>>(XWbf, att1, row_ptr, csr_src, nullptr, Gbf, nullptr, N);
  // layer 2 gemm: bf16 in, bf16 out
  gemm_bf2_k<<<nGB, 256, 0, stream>>>(Gbf, W2bf, b2, XWbf, N);
  // layer 2 edge phase + folded MLP + sigmoid
  gat_v7_k<1><<<(N+3)/4, 256, 0, stream>>>(XWbf, att2, row_ptr, csr_src, out, nullptr, wfold, N);
}

// Round 22
// 129.958 us; speedup vs baseline: 1.0324x; 1.0147x over previous
//
#include <hip/hip_runtime.h>
#include <math.h>

typedef __attribute__((ext_vector_type(2))) float f32x2;
typedef __attribute__((ext_vector_type(4))) float fx4;
typedef __attribute__((ext_vector_type(8))) short s16x8;

#define EC 64        // edge chunks
#define NRR 8        // node ranges
#define RRN 6250     // nodes per range

// ================= bf16 helpers =================

__device__ __forceinline__ unsigned pack_bf2(float lo, float hi){
  unsigned ul = __float_as_uint(lo); ul += 0x7fffu + ((ul>>16)&1u);
  unsigned uh = __float_as_uint(hi); uh += 0x7fffu + ((uh>>16)&1u);
  return (uh & 0xffff0000u) | (ul >> 16);
}

// ================= GEMM core, f32 input (split hi/lo) — layer 1 =================

__device__ __forceinline__ void gemm_core(uint4* Wl, const float* __restrict__ X,
    const float* __restrict__ b, unsigned short* __restrict__ Ybf, int nrows, int brow, int t)
{
  int wv = t >> 6, lane = t & 63;
  int r = lane & 15, kb = lane >> 4;
  int row = brow*64 + wv*16 + r;
  const float* xrow = &X[(size_t)min(row, nrows-1)*128];

  fx4 acc[8];
  #pragma unroll
  for(int c=0;c<8;c++) acc[c] = (fx4){0.f,0.f,0.f,0.f};

  #pragma unroll
  for(int kt=0;kt<4;kt++){
    int k0 = kt*32 + kb*8;
    float4 v0 = *(const float4*)&xrow[k0];
    float4 v1 = *(const float4*)&xrow[k0+4];
    float vs[8] = {v0.x,v0.y,v0.z,v0.w,v1.x,v1.y,v1.z,v1.w};
    s16x8 ahi, alo;
    #pragma unroll
    for(int j=0;j<8;j++){
      unsigned u = __float_as_uint(vs[j]);
      unsigned uh = u + 0x7fffu + ((u>>16)&1u);
      unsigned short h = (unsigned short)(uh >> 16);
      float hf = __uint_as_float(((unsigned)h)<<16);
      float lo = vs[j] - hf;
      unsigned ul = __float_as_uint(lo);
      ul += 0x7fffu + ((ul>>16)&1u);
      ahi[j] = (short)h;
      alo[j] = (short)(ul>>16);
    }
    int chunk = kt*4 + kb;
    #pragma unroll
    for(int c=0;c<8;c++){
      uint4 wb = Wl[((c*16 + r)<<4) | (chunk ^ r)];
      s16x8 bb = *(s16x8*)&wb;
      acc[c] = __builtin_amdgcn_mfma_f32_16x16x32_bf16(ahi, bb, acc[c], 0,0,0);
      acc[c] = __builtin_amdgcn_mfma_f32_16x16x32_bf16(alo, bb, acc[c], 0,0,0);
    }
  }

  __syncthreads();
  unsigned short* lds = (unsigned short*)Wl;
  unsigned short* my = lds + wv*2048;
  int colb = lane & 15;
  int rq0 = (lane>>4)*4;
  #pragma unroll
  for(int c=0;c<8;c++){
    int col = c*16 + colb;
    float bias = b[col];
    #pragma unroll
    for(int q=0;q<4;q++){
      unsigned u = __float_as_uint(acc[c][q] + bias);
      u += 0x7fffu + ((u>>16)&1u);
      my[(rq0+q)*128 + col] = (unsigned short)(u>>16);
    }
  }
  const uint4* my4 = (const uint4*)my;
  uint4* Y4 = (uint4*)Ybf;
  #pragma unroll
  for(int rr=0;rr<4;rr++){
    int idx = lane + 64*rr;
    int lrow = idx >> 4, lcol = idx & 15;
    int grow = brow*64 + wv*16 + lrow;
    if(grow < nrows)
      Y4[(size_t)grow*16 + lcol] = my4[idx];
  }
}

// ================= mega: gemm1 || fire-and-forget LDS histogram || W2 conv || fold =================

__global__ __launch_bounds__(256) void mega_k(
    const float* __restrict__ X, const float* __restrict__ W1, const float* __restrict__ b1,
    unsigned short* __restrict__ XWbf, int nrows, int nGB,
    const int* __restrict__ dst, int E, int CH,
    unsigned short* __restrict__ cnt16, int N,
    const float* __restrict__ W2, unsigned short* __restrict__ W2bf,
    const float* __restrict__ Wp1, const float* __restrict__ bp1,
    const float* __restrict__ Wp2, const float* __restrict__ bp2,
    float* __restrict__ wfold)
{
  __shared__ int smem[8192];
  int b = blockIdx.x;
  int t = threadIdx.x;

  if(b < nGB){
    uint4* Wl = (uint4*)smem;
    #pragma unroll
    for(int i=0;i<8;i++){
      int idx = t + i*256;
      int row = idx >> 4, ch = idx & 15;
      const float* wsrc = &W1[(size_t)row*128 + ch*8];
      float4 va = *(const float4*)&wsrc[0];
      float4 vb = *(const float4*)&wsrc[4];
      uint4 o;
      o.x = pack_bf2(va.x, va.y); o.y = pack_bf2(va.z, va.w);
      o.z = pack_bf2(vb.x, vb.y); o.w = pack_bf2(vb.z, vb.w);
      Wl[(row<<4) | (ch ^ (row & 15))] = o;
    }
    __syncthreads();
    gemm_core(Wl, X, b1, XWbf, nrows, b, t);
    return;
  }
  int hb = b - nGB;
  if(hb < NRR*EC){
    int r = hb >> 6, c = hb & (EC-1);
    int r0 = r*RRN, rend = min(r0+RRN, N);
    int rn = rend - r0;
    if(rn <= 0) return;
    for(int d=t; d<rn; d+=256) smem[d] = 0;
    __syncthreads();
    int e0 = c*CH, e1 = min(e0+CH, E);
    for(int e = e0+t; e < e1; e += 256){
      int d = dst[e];
      if(d >= r0 && d < rend) atomicAdd(&smem[d-r0], 1);
    }
    __syncthreads();
    unsigned short* outp = cnt16 + (size_t)c*N;
    for(int d=t; d<rn; d+=256) outp[r0+d] = (unsigned short)smem[d];
    return;
  }
  int tb = hb - NRR*EC;
  if(tb == 0){
    const float4* Ws = (const float4*)W2;
    uint2* Wd = (uint2*)W2bf;
    #pragma unroll
    for(int i=0;i<16;i++){
      int idx = t + i*256;
      float4 v = Ws[idx];
      uint2 o; o.x = pack_bf2(v.x, v.y); o.y = pack_bf2(v.z, v.w);
      Wd[idx] = o;
    }
    return;
  }
  int k = t;
  if(k < 128){
    float s = 0.f;
    for(int j=0;j<64;j++) s += Wp2[j]*Wp1[(size_t)j*128 + k];
    wfold[k] = s;
  } else if(k == 128){
    float s = bp2[0];
    for(int j=0;j<64;j++) s += Wp2[j]*bp1[j];
    wfold[128] = s;
  }
}

// ================= scan1 =================

__global__ __launch_bounds__(1024) void scan1_k(const unsigned short* __restrict__ cnt16,
    unsigned short* __restrict__ offs16, int* __restrict__ total,
    int* __restrict__ bsum, int n){
  __shared__ int ws[16];
  int i = blockIdx.x*1024 + threadIdx.x;
  int v = 0;
  if(i < n){
    int s = 0;
    #pragma unroll
    for(int c=0;c<EC;c++){
      int tc = cnt16[(size_t)c*n + i];
      offs16[(size_t)c*n + i] = (unsigned short)s;
      s += tc;
    }
    total[i] = s;
    v = s;
  }
  #pragma unroll
  for(int m=1;m<64;m<<=1) v += __shfl_xor(v, m);
  if((threadIdx.x & 63) == 0) ws[threadIdx.x >> 6] = v;
  __syncthreads();
  if(threadIdx.x == 0){
    int s = 0;
    #pragma unroll
    for(int w=0; w<16; w++) s += ws[w];
    bsum[blockIdx.x] = s;
  }
}

// ================= scan3 (merged scan2) =================

__global__ __launch_bounds__(1024) void scan3_k(const int* __restrict__ total,
    const int* __restrict__ bsum, int nb, int* __restrict__ row_ptr, int n){
  __shared__ int sm[1024];
  __shared__ int base_s;
  int t = threadIdx.x;
  if(t < 64){
    int bv = (t < nb && t < (int)blockIdx.x) ? bsum[t] : 0;
    #pragma unroll
    for(int m=1;m<64;m<<=1) bv += __shfl_xor(bv, m);
    if(t == 0) base_s = bv;
  }
  int i = blockIdx.x*1024 + t;
  int v = (i<n)? total[i] : 0;
  sm[t] = v;
  __syncthreads();
  for(int off=1; off<1024; off<<=1){
    int tv = (t>=off)? sm[t-off] : 0;
    __syncthreads();
    sm[t] += tv;
    __syncthreads();
  }
  if(i<n){
    row_ptr[i] = sm[t] - v + base_s;
    if(i == n-1) row_ptr[n] = sm[t] + base_s;
  }
}

// ================= fillC: LDS cursors, 8-deep batched loads =================

__global__ __launch_bounds__(256) void fillC_k(
    const int* __restrict__ src, const int* __restrict__ dst,
    const unsigned short* __restrict__ offs16, const int* __restrict__ row_ptr,
    int* __restrict__ csr_src, int E, int CH, int N)
{
  __shared__ int cursor[RRN];
  int b = blockIdx.x, t = threadIdx.x;
  int r = b >> 6, c = b & (EC-1);
  int r0 = r*RRN, rend = min(r0+RRN, N);
  int rn = rend - r0;
  if(rn <= 0) return;
  for(int d=t; d<rn; d+=256)
    cursor[d] = row_ptr[r0+d] + (int)offs16[(size_t)c*N + r0 + d];
  __syncthreads();
  int e0 = c*CH, e1 = min(e0+CH, E);
  for(int base = e0 + t; base < e1; base += 2048){
    int dd[8], ss[8];
    #pragma unroll
    for(int q=0;q<8;q++){
      int e = base + q*256;
      dd[q] = (e < e1) ? dst[e] : -1;
    }
    #pragma unroll
    for(int q=0;q<8;q++){
      int e = base + q*256;
      ss[q] = (e < e1) ? src[e] : 0;
    }
    #pragma unroll
    for(int q=0;q<8;q++){
      if(dd[q] >= r0 && dd[q] < rend){
        int p = atomicAdd(&cursor[dd[q]-r0], 1);
        csr_src[p] = ss[q];
      }
    }
  }
}

// ================= layer-2 GEMM: bf16 input, single MFMA =================

__global__ __launch_bounds__(256) void gemm_bf2_k(
    const unsigned short* __restrict__ Xbf, const unsigned short* __restrict__ Wbf,
    const float* __restrict__ b, unsigned short* __restrict__ Ybf, int nrows)
{
  __shared__ uint4 Wl[128*16];
  int t = threadIdx.x;
  {
    const uint4* Ws = (const uint4*)Wbf;
    #pragma unroll
    for(int i=0;i<8;i++){
      int idx = t + i*256;
      int row = idx >> 4, ch = idx & 15;
      Wl[(row<<4) | (ch ^ (row & 15))] = Ws[idx];
    }
  }
  __syncthreads();

  int wv = t >> 6, lane = t & 63;
  int r = lane & 15, kb = lane >> 4;
  int row = blockIdx.x*64 + wv*16 + r;
  const uint4* xrow = (const uint4*)&Xbf[(size_t)min(row, nrows-1)*128];

  fx4 acc[8];
  #pragma unroll
  for(int c=0;c<8;c++) acc[c] = (fx4){0.f,0.f,0.f,0.f};

  #pragma unroll
  for(int kt=0;kt<4;kt++){
    uint4 av = xrow[kt*4 + kb];
    s16x8 aa = *(s16x8*)&av;
    int chunk = kt*4 + kb;
    #pragma unroll
    for(int c=0;c<8;c++){
      uint4 wb = Wl[((c*16 + r)<<4) | (chunk ^ r)];
      s16x8 bb = *(s16x8*)&wb;
      acc[c] = __builtin_amdgcn_mfma_f32_16x16x32_bf16(aa, bb, acc[c], 0,0,0);
    }
  }

  __syncthreads();
  unsigned short* lds = (unsigned short*)Wl;
  unsigned short* my = lds + wv*2048;
  int colb = lane & 15;
  int rq0 = (lane>>4)*4;
  #pragma unroll
  for(int c=0;c<8;c++){
    int col = c*16 + colb;
    float bias = b[col];
    #pragma unroll
    for(int q=0;q<4;q++){
      unsigned u = __float_as_uint(acc[c][q] + bias);
      u += 0x7fffu + ((u>>16)&1u);
      my[(rq0+q)*128 + col] = (unsigned short)(u>>16);
    }
  }
  const uint4* my4 = (const uint4*)my;
  uint4* Y4 = (uint4*)Ybf;
  #pragma unroll
  for(int rr=0;rr<4;rr++){
    int idx = lane + 64*rr;
    int lrow = idx >> 4, lcol = idx & 15;
    int grow = blockIdx.x*64 + wv*16 + lrow;
    if(grow < nrows)
      Y4[(size_t)grow*16 + lcol] = my4[idx];
  }
}

// ================= GATv2 edge phase v8: 2 nodes/wave (halved prologue exposure) =================
// half = lane>>5 owns node; within 32-lane half: 2 edge slots (g=(lane>>4)&1) x 16 channels.
// Same 4 gathers/wave-inst as v7. Per-lane loop bounds -> exec-masked divergence.
// Merge: shfl_xor(16) ONLY (xor32 would merge the two different nodes).

#define BFLO(u) __uint_as_float((u)<<16)
#define BFHI(u) __uint_as_float((u)&0xffff0000u)
#define DPP_ADD(v, ctrl) { int _t = __builtin_amdgcn_update_dpp(0, __float_as_int(v), ctrl, 0xF, 0xF, true); (v) += __int_as_float(_t); }
#define EXP2RAW(x) __builtin_amdgcn_exp2f(x)

#define GAT_BODY(U, EXPR_EX) { \
  f32x2 x0 = {BFLO(U.x), BFHI(U.x)}; \
  f32x2 x1 = {BFLO(U.y), BFHI(U.y)}; \
  f32x2 x2 = {BFLO(U.z), BFHI(U.z)}; \
  f32x2 x3 = {BFLO(U.w), BFHI(U.w)}; \
  f32x2 v0 = xd[0]+x0, v1 = xd[1]+x1, v2 = xd[2]+x2, v3 = xd[3]+x3; \
  f32x2 l0 = __builtin_elementwise_max(v0, v0*0.2f); \
  f32x2 l1 = __builtin_elementwise_max(v1, v1*0.2f); \
  f32x2 l2 = __builtin_elementwise_max(v2, v2*0.2f); \
  f32x2 l3 = __builtin_elementwise_max(v3, v3*0.2f); \
  f32x2 p2 = l0*a[0]; p2 += l1*a[1]; p2 += l2*a[2]; p2 += l3*a[3]; \
  float p = p2.x + p2.y; \
  DPP_ADD(p, 0xB1); \
  DPP_ADD(p, 0x4E); \
  DPP_ADD(p, 0x141); \
  float ex = (EXPR_EX); \
  s += ex; \
  f32x2 e2 = {ex, ex}; \
  acc[0] += e2*x0; acc[1] += e2*x1; acc[2] += e2*x2; acc[3] += e2*x3; }

template<int FUSE>
__global__ __launch_bounds__(256) void gat_v8_k(
    const unsigned short* __restrict__ XWbf,
    const float* __restrict__ att,
    const int* __restrict__ row_ptr, const int* __restrict__ csr_src,
    float* __restrict__ outf, unsigned short* __restrict__ outbf,
    const float* __restrict__ wfold, int n)
{
  int wid = threadIdx.x >> 6, lane = threadIdx.x & 63;
  int half = lane >> 5;
  int l32 = lane & 31;
  int g = l32 >> 4;          // edge slot within half
  int cg = lane & 15;
  int c8 = cg * 8;
  int node = blockIdx.x*8 + wid*2 + half;
  bool nv = node < n;
  int nodec = nv ? node : (n-1);

  const float L2E = 1.44269504088896f;
  float4 A0 = *(const float4*)&att[c8];
  float4 A1 = *(const float4*)&att[c8+4];
  f32x2 a[4] = { {A0.x*L2E,A0.y*L2E}, {A0.z*L2E,A0.w*L2E},
                 {A1.x*L2E,A1.y*L2E}, {A1.z*L2E,A1.w*L2E} };

  const uint4* XW4 = (const uint4*)XWbf;
  uint4 du = XW4[(size_t)nodec*16 + cg];
  f32x2 xd[4] = { {BFLO(du.x),BFHI(du.x)}, {BFLO(du.y),BFHI(du.y)},
                  {BFLO(du.z),BFHI(du.z)}, {BFLO(du.w),BFHI(du.w)} };

  int beg = nv ? row_ptr[nodec]   : 0;
  int end = nv ? row_ptr[nodec+1] : 0;

  float s = 0.f;
  f32x2 acc[4] = {{0.f,0.f},{0.f,0.f},{0.f,0.f},{0.f,0.f}};

  if(end > beg){
    int i = beg;
    int sn0 = csr_src[min(beg + g, end-1)];
    uint4 u = XW4[(size_t)sn0*16 + cg];
    int sn1 = (beg+2 < end) ? csr_src[min(beg+2 + g, end-1)] : sn0;

    // main loop: full pairs only, no predication
    for(; i + 2 <= end; i += 2){
      uint4 un = XW4[(size_t)sn1*16 + cg];
      int sn2 = (i+4 < end) ? csr_src[min(i+4 + g, end-1)] : sn1;
      GAT_BODY(u, EXP2RAW(p));
      u = un; sn1 = sn2;
    }
    // tail: 1 edge, predicated
    if(i < end){
      bool ok = (i + g) < end;
      GAT_BODY(u, ok ? EXP2RAW(p) : 0.f);
    }
  }

  // merge the 2 edge slots within this half ONLY
  s += __shfl_xor(s,16);
  #pragma unroll
  for(int j=0;j<4;j++){
    acc[j].x += __shfl_xor(acc[j].x,16);
    acc[j].y += __shfl_xor(acc[j].y,16);
  }

  float inv = (s > 0.f) ? 1.f/s : 0.f;
  f32x2 o[4];
  #pragma unroll
  for(int j=0;j<4;j++){
    o[j].x = fmaxf(acc[j].x*inv, 0.f);
    o[j].y = fmaxf(acc[j].y*inv, 0.f);
  }

  if(FUSE == 0){
    if(g == 0 && nv){
      uint4 o4;
      o4.x = pack_bf2(o[0].x, o[0].y);
      o4.y = pack_bf2(o[1].x, o[1].y);
      o4.z = pack_bf2(o[2].x, o[2].y);
      o4.w = pack_bf2(o[3].x, o[3].y);
      *(uint4*)&outbf[(size_t)node*128 + c8] = o4;
    }
  } else {
    float4 wf0 = *(const float4*)&wfold[c8];
    float4 wf1 = *(const float4*)&wfold[c8+4];
    float tt = o[0].x*wf0.x + o[0].y*wf0.y + o[1].x*wf0.z + o[1].y*wf0.w
             + o[2].x*wf1.x + o[2].y*wf1.y + o[3].x*wf1.z + o[3].y*wf1.w;
    DPP_ADD(tt, 0xB1);
    DPP_ADD(tt, 0x4E);
    DPP_ADD(tt, 0x141);
    DPP_ADD(tt, 0x140);   // full 16-group sum
    if(l32 == 0 && nv)
      outf[node] = 1.f/(1.f + __expf(-(tt + wfold[128])));
  }
}

// ================= launcher =================

static inline size_t alignup(size_t v){ return (v + 255) & ~(size_t)255; }

extern "C" void kernel_launch(void* const* d_in, const int* in_sizes, int n_in,
                              void* d_out, int out_size, void* d_ws, size_t ws_size,
                              hipStream_t stream) {
  const float* x    = (const float*)d_in[0];
  const int*   ei   = (const int*)  d_in[1];
  const float* W1   = (const float*)d_in[2];
  const float* b1   = (const float*)d_in[3];
  const float* att1 = (const float*)d_in[4];
  const float* W2   = (const float*)d_in[5];
  const float* b2   = (const float*)d_in[6];
  const float* att2 = (const float*)d_in[7];
  const float* Wp1  = (const float*)d_in[8];
  const float* bp1  = (const float*)d_in[9];
  const float* Wp2  = (const float*)d_in[10];
  const float* bp2  = (const float*)d_in[11];
  float* out = (float*)d_out;

  int N = in_sizes[0] / 128;
  int E = in_sizes[1] / 2;
  int CH = (E + EC - 1) / EC;

  char* ws = (char*)d_ws;
  size_t off = 0;
  unsigned short* Gbf  = (unsigned short*)(ws + off); off = alignup(off + (size_t)N*128*sizeof(unsigned short));
  unsigned short* XWbf = (unsigned short*)(ws + off); off = alignup(off + (size_t)N*128*sizeof(unsigned short));
  int* csr_src  = (int*)(ws + off); off = alignup(off + (size_t)E*sizeof(int));
  unsigned short* cnt16  = (unsigned short*)(ws + off); off = alignup(off + (size_t)EC*N*sizeof(unsigned short));
  unsigned short* offs16 = (unsigned short*)(ws + off); off = alignup(off + (size_t)EC*N*sizeof(unsigned short));
  int* row_ptr  = (int*)(ws + off); off = alignup(off + (size_t)(N+1)*sizeof(int));
  int* total    = (int*)(ws + off); off = alignup(off + (size_t)N*sizeof(int));
  int* bsum     = (int*)(ws + off); off = alignup(off + 1024*sizeof(int));
  unsigned short* W2bf = (unsigned short*)(ws + off); off = alignup(off + 128*128*sizeof(unsigned short));
  float* wfold  = (float*)(ws + off); off = alignup(off + 129*sizeof(float));

  const int* esrc = ei;
  const int* edst = ei + E;

  int nGB = (N + 63) / 64;
  int nb = (N + 1023) / 1024;

  // gemm1 || CSR histogram (fire-and-forget) || W2 convert || fold
  mega_k<<<nGB + NRR*EC + 2, 256, 0, stream>>>(
      x, W1, b1, XWbf, N, nGB,
      edst, E, CH, cnt16, N,
      W2, W2bf, Wp1, bp1, Wp2, bp2, wfold);

  scan1_k<<<nb, 1024, 0, stream>>>(cnt16, offs16, total, bsum, N);
  scan3_k<<<nb, 1024, 0, stream>>>(total, bsum, nb, row_ptr, N);
  fillC_k<<<NRR*EC, 256, 0, stream>>>(esrc, edst, offs16, row_ptr, csr_src, E, CH, N);

  int gatB = (N + 7) / 8;
  // layer 1 edge phase -> bf16 h
  gat_v8_k<0><<<gatB, 256, 0, stream>>>(XWbf, att1, row_ptr, csr_src, nullptr, Gbf, nullptr, N);
  // layer 2 gemm: bf16 in, bf16 out
  gemm_bf2_k<<<nGB, 256, 0, stream>>>(Gbf, W2bf, b2, XWbf, N);
  // layer 2 edge phase + folded MLP + sigmoid
  gat_v8_k<1><<<gatB, 256, 0, stream>>>(XWbf, att2, row_ptr, csr_src, out, nullptr, wfold, N);
}